// Round 15
// baseline (713.502 us; speedup 1.0000x reference)
//
#include <hip/hip_runtime.h>

// x[2048,64,2] -> MLP(2->16 relu ->16) -> 8x LSTM(H=64) -> MLP(64->32 relu ->4)
// fp32 in/out. LSTM via 2-term split-bf16 MFMA (R14-verified, absmax ~1e-3 passing).
//
// Round 18: QUAD fusion — 4 layers per block (enabled by R14's 64-VGPR weights).
//   2 dispatches: layers 0-3, then 4-7. grid 256 x 1024 threads (16 waves,
//   4/SIMD, __launch_bounds__(1024,4) caps VGPR at 128). M=8 rows/block.
//   Waves 4l..4l+3 run layer p0+l. Chain of verified R12 pair-links:
//     L0: x (pA parity) + own h (ring0);  writes ring0, gated by mm[1].
//     L1/L2: input ring[l-1] slot t (preload -> release mm[l]), own h ring[l]
//            slot t-1; writes ring[l] slot t, gated by mm[l+1] (3-step slack).
//     L3: input ring2 (release mm[3]), own h parity pH; global out (P / bufH).
//   ALL sync = workgroup-scope LDS counters (cc[0..3], mm[1..3]) — the proven
//   pattern; no agent-scope flags (R16's failure mode excluded).
//   Sequential depth 260 -> ~140 supersteps. Cell math verbatim from R14.
//   Prio: L0 base 1 / MFMA 2 (feeds everyone); others base 0 / MFMA 1.

#define BATCH 2048
#define TT 64
#define HH 64
#define RS 72     // h-panel row stride in shorts (64 cols + 8 pad)

typedef short bf16x8 __attribute__((ext_vector_type(8)));
typedef float f32x4 __attribute__((ext_vector_type(4)));

__device__ __forceinline__ float sigmoid_fast(float x) {
    return __builtin_amdgcn_rcpf(1.f + __expf(-x));
}
__device__ __forceinline__ float tanh_fast(float x) {
    float e = __expf(-2.f * x);
    e = fminf(e, 1e30f);          // keep 1+e finite so rcp>0: tanh(-big) -> -1, not NaN
    return (1.f - e) * __builtin_amdgcn_rcpf(1.f + e);
}
__device__ __forceinline__ void split2(float x, unsigned short& hi, unsigned short& lo) {
    const unsigned u = __float_as_uint(x);
    hi = (unsigned short)(u >> 16);
    const float r = x - __uint_as_float(u & 0xFFFF0000u);  // exact
    lo = (unsigned short)(__float_as_uint(r) >> 16);
}
__device__ __forceinline__ unsigned short bf16_rne(float x) {
    const unsigned u = __float_as_uint(x);
    return (unsigned short)((u + 0x7FFFu + ((u >> 16) & 1u)) >> 16);
}
__device__ __forceinline__ void wg_wait(int* c, int v) {
    while (__hip_atomic_load(c, __ATOMIC_ACQUIRE, __HIP_MEMORY_SCOPE_WORKGROUP) < v) {}
}
__device__ __forceinline__ void wg_bump(int* c, int lane) {
    if (lane == 0)
        __hip_atomic_fetch_add(c, 1, __ATOMIC_RELEASE, __HIP_MEMORY_SCOPE_WORKGROUP);
}

// ---------------- input MLP: 2 -> 16 relu -> 16 ----------------
__global__ __launch_bounds__(256)
void mlp_in_kernel(const float* __restrict__ x,
                   const float* __restrict__ w1, const float* __restrict__ b1,
                   const float* __restrict__ w2, const float* __restrict__ b2,
                   float* __restrict__ out) {
    const int gid = blockIdx.x * 256 + threadIdx.x;
    const float x0 = x[gid * 2 + 0];
    const float x1 = x[gid * 2 + 1];
    float hid[16];
#pragma unroll
    for (int j = 0; j < 16; ++j) {
        float v = fmaf(x1, w1[j * 2 + 1], fmaf(x0, w1[j * 2 + 0], b1[j]));
        hid[j] = fmaxf(0.f, v);
    }
    float o[16];
#pragma unroll
    for (int oo = 0; oo < 16; ++oo) {
        float acc = b2[oo];
#pragma unroll
        for (int j = 0; j < 16; ++j) acc = fmaf(hid[j], w2[oo * 16 + j], acc);
        o[oo] = acc;
    }
    float4* op = (float4*)(out + gid * 16);
#pragma unroll
    for (int q = 0; q < 4; ++q) {
        float4 v;
        v.x = o[q * 4 + 0]; v.y = o[q * 4 + 1]; v.z = o[q * 4 + 2]; v.w = o[q * 4 + 3];
        op[q] = v;
    }
}

// ---------------- quad LSTM: 4 layers/block, M=8, 1024 threads ----------------
// L0 K layout: [0,IPADA) = x (pA); [IPADA,IPADA+64) = h_L0 (ring0 slot t-1).
// L1/L2:       [0,64) = h_{l-1} (ring[l-1] slot t); [64,128) = own h (ring[l] slot t-1).
// L3:          [0,64) = h_L2 (ring2 slot t); [64,128) = own h (pH parity).
template <int IA, int IPADA>
__global__ __launch_bounds__(1024, 4)
void lstm_quad(const float* __restrict__ xmlp,   // L0 input iff IA==16
               const unsigned* __restrict__ Pin, // L0 input iff IA==64
               unsigned* __restrict__ Pout,      // L3 out iff !last
               float* __restrict__ houtf,        // L3 out iff last
               const int p0, const int last,
               const float* __restrict__ w_ih0, const float* __restrict__ w_hh0,
               const float* __restrict__ b_ih0, const float* __restrict__ b_hh0,
               const float* __restrict__ w_ih, const float* __restrict__ w_hh,
               const float* __restrict__ b_ih, const float* __restrict__ b_hh) {
    constexpr int KTA = (IPADA + 64) / 32;  // L0 total k-tiles
    constexpr int KTX = IPADA / 32;         // L0 k-tiles in pA (x region)
    constexpr int LDPA = IPADA + 8;         // pA row stride (shorts)
    __shared__ __align__(16) unsigned short pAh[2][16 * LDPA], pAl[2][16 * LDPA];
    __shared__ __align__(16) unsigned short rh[3][4][16 * RS], rl[3][4][16 * RS];
    __shared__ __align__(16) unsigned short pHh[2][16 * RS], pHl[2][16 * RS];
    __shared__ int cc[4], mm[4];

    const int tid = threadIdx.x;
    const int wv = tid >> 6, lane = tid & 63, l16 = lane & 15, quad = lane >> 4;
    const int l = wv >> 2;     // layer within quad: 0..3
    const int wg = wv & 3;     // j-group within layer
    const int base = blockIdx.x * 8;
    const bool lo32 = (lane < 32);
    const int bpi = (lane & 31) << 2;   // ds_bpermute byte index: partner lane-32

    if (tid < 4) { cc[tid] = 0; mm[tid] = 0; }
    for (int e = tid; e < 2 * 16 * LDPA; e += 1024) { (&pAh[0][0])[e] = 0; (&pAl[0][0])[e] = 0; }
    for (int e = tid; e < 3 * 4 * 16 * RS; e += 1024) { (&rh[0][0][0])[e] = 0; (&rl[0][0][0])[e] = 0; }
    for (int e = tid; e < 2 * 16 * RS; e += 1024) { (&pHh[0][0])[e] = 0; (&pHl[0][0])[e] = 0; }

    // per-wave layer params (wave-uniform)
    const int L = p0 + l;
    const float *wih, *whh, *bi, *bh;
    int I, IPAD, KT;
    if (L == 0) { wih = w_ih0; whh = w_hh0; bi = b_ih0; bh = b_hh0; I = IA; IPAD = IPADA; KT = KTA; }
    else {
        const int li = L - 1;
        wih = w_ih + (size_t)li * 256 * 64; whh = w_hh + (size_t)li * 256 * 64;
        bi = b_ih + li * 256; bh = b_hh + li * 256;
        I = 64; IPAD = 64; KT = 4;
    }

    // --- weight B-fragments (bf16 RNE), gate-per-tile: tile gt = gate gt ---
    const int jg = 16 * wg + l16;
    bf16x8 bhi[4][4];  // [kt][gt]
    float bsum[4];
#pragma unroll
    for (int gt = 0; gt < 4; ++gt) {
        const int n = gt * 64 + jg;
        bsum[gt] = bi[n] + bh[n];
#pragma unroll
        for (int kt = 0; kt < 4; ++kt) {
            bf16x8 vh = {0, 0, 0, 0, 0, 0, 0, 0};
            if (kt < KT) {
#pragma unroll
                for (int j = 0; j < 8; ++j) {
                    const int k = kt * 32 + quad * 8 + j;
                    float w = 0.f;
                    if (k < I) w = wih[n * I + k];
                    else if (k >= IPAD) w = whh[n * 64 + (k - IPAD)];
                    vh[j] = (short)bf16_rne(w);
                }
            }
            bhi[kt][gt] = vh;
        }
    }

    // c-state: 2 cells/lane, rows row0+r, col jg
    float cs[2] = {0.f, 0.f};
    const int row0 = (quad & 1) * 4 + ((quad >> 1) << 1);

    // --- staging setup (L0 waves = tid 0..255): x(0) -> pA[0]; prefetch x(1) ---
    float2 xr2 = {0.f, 0.f};
    uint2 xru = {0u, 0u};
    int sr = 0, sc = 0, srd = 0;
    bool stg = false;
    if (l == 0 && wv < 4) {
        if (IA == 16) {
            stg = (tid < 128);
            sr = tid >> 3; sc = (tid & 7) * 2;       // sr 0..15; rows 8-15 junk pad
            srd = base + (sr & 7);                    // clamp global read row
            if (stg) {
                xr2 = *(const float2*)&xmlp[((size_t)srd * TT + 0) * 16 + sc];
                unsigned short h0, l0, h1, l1;
                split2(xr2.x, h0, l0); split2(xr2.y, h1, l1);
                *(unsigned*)&pAh[0][sr * LDPA + sc] = ((unsigned)h1 << 16) | h0;
                *(unsigned*)&pAl[0][sr * LDPA + sc] = ((unsigned)l1 << 16) | l0;
                xr2 = *(const float2*)&xmlp[((size_t)srd * TT + 1) * 16 + sc];
            }
        } else {
            stg = (tid < 256);
            sr = tid >> 5; sc = (tid & 31) * 2;
            srd = base + sr;
            if (stg) {
                xru = *(const uint2*)&Pin[((size_t)srd * TT + 0) * 64 + sc];
                *(unsigned*)&pAh[0][sr * LDPA + sc] = (xru.y & 0xFFFF0000u) | (xru.x >> 16);
                *(unsigned*)&pAl[0][sr * LDPA + sc] = (xru.y << 16) | (xru.x & 0xFFFFu);
                xru = *(const uint2*)&Pin[((size_t)srd * TT + 1) * 64 + sc];
            }
        }
    }
    __syncthreads();   // panels + counters ready; last barrier in the kernel

    if (l == 0) {
        // ============ L0: x + own-ring recurrence; publishes ring0 ============
        __builtin_amdgcn_s_setprio(1);
        for (int t = 0; t < TT; ++t) {
            const int pb = t & 1;
            const int rsl = t & 3, rpr = (t + 3) & 3;
            if (t) wg_wait(&cc[0], 4 * t);
            // stage x(t+1) -> pA[pb^1]; prefetch x(t+2)
            if (stg) {
                if (IA == 16) {
                    unsigned short h0, l0, h1, l1;
                    split2(xr2.x, h0, l0); split2(xr2.y, h1, l1);
                    *(unsigned*)&pAh[pb ^ 1][sr * LDPA + sc] = ((unsigned)h1 << 16) | h0;
                    *(unsigned*)&pAl[pb ^ 1][sr * LDPA + sc] = ((unsigned)l1 << 16) | l0;
                    const int tp = (t + 2) & (TT - 1);
                    xr2 = *(const float2*)&xmlp[((size_t)srd * TT + tp) * 16 + sc];
                } else {
                    *(unsigned*)&pAh[pb ^ 1][sr * LDPA + sc] = (xru.y & 0xFFFF0000u) | (xru.x >> 16);
                    *(unsigned*)&pAl[pb ^ 1][sr * LDPA + sc] = (xru.y << 16) | (xru.x & 0xFFFFu);
                    const int tp = (t + 2) & (TT - 1);
                    xru = *(const uint2*)&Pin[((size_t)srd * TT + tp) * 64 + sc];
                }
            }
            // preload: x from pA[pb], own h from ring0 slot rpr
            bf16x8 ahi[4], alo[4];
#pragma unroll
            for (int kt = 0; kt < KTA; ++kt) {
                if (kt < KTX) {
                    const int aoff = l16 * LDPA + kt * 32 + quad * 8;
                    ahi[kt] = *(const bf16x8*)&pAh[pb][aoff];
                    alo[kt] = *(const bf16x8*)&pAl[pb][aoff];
                } else {
                    const int aoff = l16 * RS + (kt - KTX) * 32 + quad * 8;
                    ahi[kt] = *(const bf16x8*)&rh[0][rpr][aoff];
                    alo[kt] = *(const bf16x8*)&rl[0][rpr][aoff];
                }
            }
            f32x4 a0[4], a1[4];
#pragma unroll
            for (int gt = 0; gt < 4; ++gt) {
                a0[gt][0] = bsum[gt]; a0[gt][1] = bsum[gt];
                a0[gt][2] = bsum[gt]; a0[gt][3] = bsum[gt];
                a1[gt] = (f32x4){0.f, 0.f, 0.f, 0.f};
            }
            __builtin_amdgcn_s_setprio(2);
#pragma unroll
            for (int kt = 0; kt < KTA; ++kt) {
#pragma unroll
                for (int gt = 0; gt < 4; ++gt) {
                    a0[gt] = __builtin_amdgcn_mfma_f32_16x16x32_bf16(ahi[kt], bhi[kt][gt], a0[gt], 0, 0, 0);
                    a1[gt] = __builtin_amdgcn_mfma_f32_16x16x32_bf16(alo[kt], bhi[kt][gt], a1[gt], 0, 0, 0);
                }
            }
            __builtin_amdgcn_s_setprio(1);
            f32x4 s4[4];
#pragma unroll
            for (int gt = 0; gt < 4; ++gt) s4[gt] = a0[gt] + a1[gt];
            float gk[4][2];
#pragma unroll
            for (int gt = 0; gt < 4; ++gt) {
#pragma unroll
                for (int r = 0; r < 2; ++r) {
                    const float up = __uint_as_float(
                        __builtin_amdgcn_ds_bpermute(bpi, __float_as_uint(s4[gt][r + 2])));
                    gk[gt][r] = lo32 ? s4[gt][r] : up;
                }
            }
            float hv[2];
#pragma unroll
            for (int r = 0; r < 2; ++r) {
                const float iv = sigmoid_fast(gk[0][r]);
                const float fv = sigmoid_fast(gk[1][r]);
                const float gv = tanh_fast(gk[2][r]);
                const float ov = sigmoid_fast(gk[3][r]);
                const float cn = fv * cs[r] + iv * gv;
                cs[r] = cn;
                hv[r] = ov * tanh_fast(cn);
            }
            if (t >= 4) wg_wait(&mm[1], 4 * (t - 3));   // L1 preloaded slot rsl
#pragma unroll
            for (int r = 0; r < 2; ++r) {
                const int R = row0 + r;
                unsigned short h_, l_;
                split2(hv[r], h_, l_);
                rh[0][rsl][R * RS + jg] = h_;
                rl[0][rsl][R * RS + jg] = l_;
            }
            wg_bump(&cc[0], lane);
        }
    } else if (l < 3) {
        // ============ L1/L2: ring[l-1] in, ring[l] recurrence+out ============
        for (int t = 0; t < TT; ++t) {
            const int rsl = t & 3, rpr = (t + 3) & 3;
            if (t) wg_wait(&cc[l], 4 * t);
            wg_wait(&cc[l - 1], 4 * (t + 1));   // input h(t) ready (pre-satisfied when lagging)
            bf16x8 ahi[4], alo[4];
#pragma unroll
            for (int kt = 0; kt < 2; ++kt) {
                const int aoff = l16 * RS + kt * 32 + quad * 8;
                ahi[kt] = *(const bf16x8*)&rh[l - 1][rsl][aoff];
                alo[kt] = *(const bf16x8*)&rl[l - 1][rsl][aoff];
            }
            wg_bump(&mm[l], lane);   // release: upstream may overwrite slot rsl (at t+4)
#pragma unroll
            for (int kt = 2; kt < 4; ++kt) {
                const int aoff = l16 * RS + (kt - 2) * 32 + quad * 8;
                ahi[kt] = *(const bf16x8*)&rh[l][rpr][aoff];
                alo[kt] = *(const bf16x8*)&rl[l][rpr][aoff];
            }
            f32x4 a0[4], a1[4];
#pragma unroll
            for (int gt = 0; gt < 4; ++gt) {
                a0[gt][0] = bsum[gt]; a0[gt][1] = bsum[gt];
                a0[gt][2] = bsum[gt]; a0[gt][3] = bsum[gt];
                a1[gt] = (f32x4){0.f, 0.f, 0.f, 0.f};
            }
            __builtin_amdgcn_s_setprio(1);
#pragma unroll
            for (int kt = 0; kt < 4; ++kt) {
#pragma unroll
                for (int gt = 0; gt < 4; ++gt) {
                    a0[gt] = __builtin_amdgcn_mfma_f32_16x16x32_bf16(ahi[kt], bhi[kt][gt], a0[gt], 0, 0, 0);
                    a1[gt] = __builtin_amdgcn_mfma_f32_16x16x32_bf16(alo[kt], bhi[kt][gt], a1[gt], 0, 0, 0);
                }
            }
            __builtin_amdgcn_s_setprio(0);
            f32x4 s4[4];
#pragma unroll
            for (int gt = 0; gt < 4; ++gt) s4[gt] = a0[gt] + a1[gt];
            float gk[4][2];
#pragma unroll
            for (int gt = 0; gt < 4; ++gt) {
#pragma unroll
                for (int r = 0; r < 2; ++r) {
                    const float up = __uint_as_float(
                        __builtin_amdgcn_ds_bpermute(bpi, __float_as_uint(s4[gt][r + 2])));
                    gk[gt][r] = lo32 ? s4[gt][r] : up;
                }
            }
            float hv[2];
#pragma unroll
            for (int r = 0; r < 2; ++r) {
                const float iv = sigmoid_fast(gk[0][r]);
                const float fv = sigmoid_fast(gk[1][r]);
                const float gv = tanh_fast(gk[2][r]);
                const float ov = sigmoid_fast(gk[3][r]);
                const float cn = fv * cs[r] + iv * gv;
                cs[r] = cn;
                hv[r] = ov * tanh_fast(cn);
            }
            if (t >= 4) wg_wait(&mm[l + 1], 4 * (t - 3));   // downstream preloaded slot rsl
#pragma unroll
            for (int r = 0; r < 2; ++r) {
                const int R = row0 + r;
                unsigned short h_, l_;
                split2(hv[r], h_, l_);
                rh[l][rsl][R * RS + jg] = h_;
                rl[l][rsl][R * RS + jg] = l_;
            }
            wg_bump(&cc[l], lane);
        }
    } else {
        // ============ L3: ring2 in, pH parity recurrence, global out ============
        for (int t = 0; t < TT; ++t) {
            const int pb = t & 1;
            const int rsl = t & 3;
            if (t) wg_wait(&cc[3], 4 * t);
            wg_wait(&cc[2], 4 * (t + 1));
            bf16x8 ahi[4], alo[4];
#pragma unroll
            for (int kt = 0; kt < 2; ++kt) {
                const int aoff = l16 * RS + kt * 32 + quad * 8;
                ahi[kt] = *(const bf16x8*)&rh[2][rsl][aoff];
                alo[kt] = *(const bf16x8*)&rl[2][rsl][aoff];
            }
            wg_bump(&mm[3], lane);   // release: L2 may overwrite slot rsl (at t+4)
#pragma unroll
            for (int kt = 2; kt < 4; ++kt) {
                const int aoff = l16 * RS + (kt - 2) * 32 + quad * 8;
                ahi[kt] = *(const bf16x8*)&pHh[pb ^ 1][aoff];
                alo[kt] = *(const bf16x8*)&pHl[pb ^ 1][aoff];
            }
            f32x4 a0[4], a1[4];
#pragma unroll
            for (int gt = 0; gt < 4; ++gt) {
                a0[gt][0] = bsum[gt]; a0[gt][1] = bsum[gt];
                a0[gt][2] = bsum[gt]; a0[gt][3] = bsum[gt];
                a1[gt] = (f32x4){0.f, 0.f, 0.f, 0.f};
            }
            __builtin_amdgcn_s_setprio(1);
#pragma unroll
            for (int kt = 0; kt < 4; ++kt) {
#pragma unroll
                for (int gt = 0; gt < 4; ++gt) {
                    a0[gt] = __builtin_amdgcn_mfma_f32_16x16x32_bf16(ahi[kt], bhi[kt][gt], a0[gt], 0, 0, 0);
                    a1[gt] = __builtin_amdgcn_mfma_f32_16x16x32_bf16(alo[kt], bhi[kt][gt], a1[gt], 0, 0, 0);
                }
            }
            __builtin_amdgcn_s_setprio(0);
            f32x4 s4[4];
#pragma unroll
            for (int gt = 0; gt < 4; ++gt) s4[gt] = a0[gt] + a1[gt];
            float gk[4][2];
#pragma unroll
            for (int gt = 0; gt < 4; ++gt) {
#pragma unroll
                for (int r = 0; r < 2; ++r) {
                    const float up = __uint_as_float(
                        __builtin_amdgcn_ds_bpermute(bpi, __float_as_uint(s4[gt][r + 2])));
                    gk[gt][r] = lo32 ? s4[gt][r] : up;
                }
            }
#pragma unroll
            for (int r = 0; r < 2; ++r) {
                const float iv = sigmoid_fast(gk[0][r]);
                const float fv = sigmoid_fast(gk[1][r]);
                const float gv = tanh_fast(gk[2][r]);
                const float ov = sigmoid_fast(gk[3][r]);
                const float cn = fv * cs[r] + iv * gv;
                cs[r] = cn;
                const float h = ov * tanh_fast(cn);
                const int R = row0 + r;
                unsigned short h_, l_;
                split2(h, h_, l_);
                pHh[pb][R * RS + jg] = h_;
                pHl[pb][R * RS + jg] = l_;
                if (!last) {
                    Pout[((size_t)(base + R) * TT + t) * 64 + jg] =
                        ((unsigned)h_ << 16) | (unsigned)l_;
                } else {
                    houtf[((size_t)(base + R) * TT + t) * HH + jg] = h;
                }
            }
            wg_bump(&cc[3], lane);
        }
    }
}

// ---------------- output MLP: 64 -> 32 relu -> 4 ----------------
__global__ __launch_bounds__(256)
void mlp_out_kernel(const float* __restrict__ hin,
                    const float* __restrict__ wo1, const float* __restrict__ bo1,
                    const float* __restrict__ wo2, const float* __restrict__ bo2,
                    float* __restrict__ out) {
    __shared__ __align__(16) float wo1_s[32 * 64];
    __shared__ float bo1_s[32];
    __shared__ float wo2_s[4 * 32];
    __shared__ float bo2_s[4];
    const int tid = threadIdx.x;
    for (int e = tid; e < 32 * 64; e += 256) wo1_s[e] = wo1[e];
    if (tid < 32) bo1_s[tid] = bo1[tid];
    if (tid < 128) wo2_s[tid] = wo2[tid];
    if (tid < 4) bo2_s[tid] = bo2[tid];
    __syncthreads();

    const int gid = blockIdx.x * 256 + tid;
    const float4* hv = (const float4*)(hin + gid * 64);
    float4 h[16];
#pragma unroll
    for (int q = 0; q < 16; ++q) h[q] = hv[q];

    float m1[32];
#pragma unroll
    for (int o = 0; o < 32; ++o) {
        float acc = bo1_s[o];
        const float4* wrow = (const float4*)(wo1_s + o * 64);
#pragma unroll
        for (int q = 0; q < 16; ++q) {
            const float4 w = wrow[q];
            acc = fmaf(h[q].x, w.x, acc);
            acc = fmaf(h[q].y, w.y, acc);
            acc = fmaf(h[q].z, w.z, acc);
            acc = fmaf(h[q].w, w.w, acc);
        }
        m1[o] = fmaxf(0.f, acc);
    }
    float r[4];
#pragma unroll
    for (int q = 0; q < 4; ++q) {
        float acc = bo2_s[q];
#pragma unroll
        for (int o = 0; o < 32; ++o) acc = fmaf(m1[o], wo2_s[q * 32 + o], acc);
        r[q] = acc;
    }
    float4 res;
    res.x = r[0]; res.y = r[1]; res.z = r[2]; res.w = r[3];
    ((float4*)out)[gid] = res;
}

extern "C" void kernel_launch(void* const* d_in, const int* in_sizes, int n_in,
                              void* d_out, int out_size, void* d_ws, size_t ws_size,
                              hipStream_t stream) {
    const float* x     = (const float*)d_in[0];
    const float* w1    = (const float*)d_in[1];
    const float* b1    = (const float*)d_in[2];
    const float* w2    = (const float*)d_in[3];
    const float* b2    = (const float*)d_in[4];
    const float* w_ih0 = (const float*)d_in[5];
    const float* w_hh0 = (const float*)d_in[6];
    const float* b_ih0 = (const float*)d_in[7];
    const float* b_hh0 = (const float*)d_in[8];
    const float* w_ih  = (const float*)d_in[9];
    const float* w_hh  = (const float*)d_in[10];
    const float* b_ih  = (const float*)d_in[11];
    const float* b_hh  = (const float*)d_in[12];
    const float* wo1   = (const float*)d_in[13];
    const float* bo1   = (const float*)d_in[14];
    const float* wo2   = (const float*)d_in[15];
    const float* bo2   = (const float*)d_in[16];

    // workspace: buf_mlp B*T*16 f32 (8 MB) | P B*T*64 u32 packed (32 MB) | bufH B*T*64 f32 (32 MB)
    float* buf_mlp = (float*)d_ws;
    unsigned* P = (unsigned*)(buf_mlp + (size_t)BATCH * TT * 16);
    float* bufH = (float*)(P + (size_t)BATCH * TT * 64);

    const int nbt_blocks = (BATCH * TT) / 256;  // 512

    mlp_in_kernel<<<nbt_blocks, 256, 0, stream>>>(x, w1, b1, w2, b2, buf_mlp);

    // quad 0: layers 0-3 (x from MLP, out -> P)
    lstm_quad<16, 32><<<BATCH / 8, 1024, 0, stream>>>(
        buf_mlp, nullptr, P, bufH, 0, 0,
        w_ih0, w_hh0, b_ih0, b_hh0, w_ih, w_hh, b_ih, b_hh);

    // quad 1: layers 4-7 (in from P, out -> bufH fp32)
    lstm_quad<64, 64><<<BATCH / 8, 1024, 0, stream>>>(
        nullptr, P, nullptr, bufH, 4, 1,
        w_ih0, w_hh0, b_ih0, b_hh0, w_ih, w_hh, b_ih, b_hh);

    mlp_out_kernel<<<nbt_blocks, 256, 0, stream>>>(bufH, wo1, bo1, wo2, bo2, (float*)d_out);
}